// Round 9
// baseline (133.689 us; speedup 1.0000x reference)
//
#include <hip/hip_runtime.h>
#include <hip/hip_bf16.h>

// GAT forward on MI355X. N=4096, IN_F=512, OUT_F=64, HEADS=4, alpha=0.2.
//
// R8 post-mortem: i-reuse (L2-traffic halving) is the lever that works.
// R9: attn v4 -- 64 i-rows/block (256 blocks, 16 waves: 8 j-eighths x 2
// i-halves), L2 traffic 134->67 MB; 3-sync LDS tree combine (80 KB).
// stage1 folded away: gemm reads x/W fp32 directly (hidden under adjpack).
// K1: gemmfuse+adjpack    K2: attn

#define NN 4096
#define KF 512
#define NF 256

typedef __attribute__((ext_vector_type(8))) short bf16x8;
typedef __attribute__((ext_vector_type(4))) short s16x4;
typedef __attribute__((ext_vector_type(4))) float f32x4;

union AB8 { bf16x8 v; short2 h[4]; short s[8]; int4 i4; };
union ST4 { s16x4 v; short2 h[2]; };
union I64 { long v; int i[2]; };

__device__ __forceinline__ short f2bf(float f) {
    union { float f; unsigned u; } v; v.f = f;
    unsigned r = v.u + 0x7fffu + ((v.u >> 16) & 1u);  // RNE (finite only)
    return (short)(r >> 16);
}
__device__ __forceinline__ short2 pkbf(float a, float b) {
    __hip_bfloat162 t = __float22bfloat162_rn(make_float2(a, b));
    union { __hip_bfloat162 v; short2 s; } u; u.v = t;
    return u.s;
}
__device__ __forceinline__ int pkfp8x4(float a, float b, float c, float d) {
    int p = __builtin_amdgcn_cvt_pk_fp8_f32(a, b, 0, false);
    p     = __builtin_amdgcn_cvt_pk_fp8_f32(c, d, p, true);
    return p;
}

// ---------------- K1: gemmfuse (bid<256) + adjpack (bid>=256) ----------------
__global__ __launch_bounds__(256) void stage2(const float* __restrict__ x,
                                              const float* __restrict__ W,
                                              const float* __restrict__ a,
                                              const int* __restrict__ adj,
                                              unsigned char* __restrict__ VtF8,
                                              float* __restrict__ ipk,
                                              float2* __restrict__ jpk,
                                              unsigned* __restrict__ pT) {
    if (blockIdx.x < 256) {
        // ---- gemm: h = x@W -> fp8 V-fragments + ipk/jpk (x, W read direct) ----
        const int lane = threadIdx.x & 63, wv = threadIdx.x >> 6;
        const int q = lane >> 4, r = lane & 15;
        const int jb32 = blockIdx.x >> 1, ch = blockIdx.x & 1;
        const int rg = wv >> 1, hd = ch * 2 + (wv & 1);
        const int jgrp = jb32 * 2 + rg;

        const float* xp = x + (size_t)(jgrp * 16 + r) * KF + q * 8;
        const float* wp = W + hd * 64 + r;   // + (kblk*32+q*8+e)*NF + nt*16

        f32x4 acc[4] = {};
        #pragma unroll 2
        for (int kblk = 0; kblk < 16; kblk++) {
            float4 xa = *(const float4*)(xp + kblk * 32);
            float4 xb = *(const float4*)(xp + kblk * 32 + 4);
            AB8 av;
            av.h[0] = pkbf(xa.x, xa.y);  av.h[1] = pkbf(xa.z, xa.w);
            av.h[2] = pkbf(xb.x, xb.y);  av.h[3] = pkbf(xb.z, xb.w);
            const float* wk = wp + (size_t)(kblk * 32 + q * 8) * NF;
            #pragma unroll
            for (int nt = 0; nt < 4; nt++) {
                AB8 bv;
                #pragma unroll
                for (int e = 0; e < 8; e++) bv.s[e] = f2bf(wk[e * NF + nt * 16]);
                acc[nt] = __builtin_amdgcn_mfma_f32_16x16x32_bf16(av.v, bv.v, acc[nt], 0, 0, 0);
            }
        }
        const int base = rg * 16 + q * 4;
        const int qa = base >> 3, e0 = base & 7;
        #pragma unroll
        for (int nt = 0; nt < 4; nt++) {
            size_t slot = (size_t)(((jb32 * 4 + hd) * 4 + nt) * 64 + qa * 16 + r);
            *(int*)(VtF8 + slot * 8 + e0) = pkfp8x4(acc[nt][0], acc[nt][1], acc[nt][2], acc[nt][3]);
        }
        float as[4], at[4];
        #pragma unroll
        for (int nt = 0; nt < 4; nt++) { as[nt] = a[nt * 16 + r]; at[nt] = a[64 + nt * 16 + r]; }
        f32x4 sp = {}, tp = {};
        #pragma unroll
        for (int nt = 0; nt < 4; nt++)
            #pragma unroll
            for (int reg = 0; reg < 4; reg++) {
                sp[reg] += acc[nt][reg] * as[nt];
                tp[reg] += acc[nt][reg] * at[nt];
            }
        #pragma unroll
        for (int d = 1; d < 16; d <<= 1)
            #pragma unroll
            for (int reg = 0; reg < 4; reg++) {
                sp[reg] += __shfl_xor(sp[reg], d, 64);
                tp[reg] += __shfl_xor(tp[reg], d, 64);
            }
        if (r == 0) {
            #pragma unroll
            for (int reg = 0; reg < 4; reg++) {
                int j = jb32 * 32 + rg * 16 + q * 4 + reg;
                ipk[hd * NN + j] = __expf(-0.8f * sp[reg]);
                jpk[hd * NN + j] = make_float2(__expf(tp[reg]), __expf(0.2f * tp[reg]));
            }
        }
    } else {
        // ---- adjpack: adj -> transposed bit groups ----
        int gw   = ((blockIdx.x - 256) * 256 + threadIdx.x) >> 6;
        int lane = threadIdx.x & 63;
        int i = gw >> 4, seg = gw & 15;
        const int* ap = adj + (size_t)i * NN + seg * 256 + lane;
        unsigned long long b0 = __ballot(ap[0]   != 0);
        unsigned long long b1 = __ballot(ap[64]  != 0);
        unsigned long long b2 = __ballot(ap[128] != 0);
        unsigned long long b3 = __ballot(ap[192] != 0);
        if (lane == 0) {
            *(uint4*)(pT + ((size_t)(seg * 2    ) * NN + i) * 4) =
                make_uint4((unsigned)b0, (unsigned)(b0 >> 32), (unsigned)b1, (unsigned)(b1 >> 32));
            *(uint4*)(pT + ((size_t)(seg * 2 + 1) * NN + i) * 4) =
                make_uint4((unsigned)b2, (unsigned)(b2 >> 32), (unsigned)b3, (unsigned)(b3 >> 32));
        }
    }
}

// ---------------- K2: attn v4 -- 64 i-rows/block, LUT mask, fp8 P@V ----------------
// grid 256 = 64 itile64 x 4 heads; block 1024 = 16 waves: js = wv&7 (j-eighth),
// ih = wv>>3 (i-half). Each wave: 2 i-tiles sharing V/jpk loads (R8 inner loop).
__global__ __launch_bounds__(1024, 4)
void gat_attn(const uint4* __restrict__ pT4, const float* __restrict__ ipk,
              const float* __restrict__ jpkf, const unsigned char* __restrict__ VtF8,
              float* __restrict__ out) {
    const int lane = threadIdx.x & 63, wv = threadIdx.x >> 6;
    const int js = wv & 7, ih = wv >> 3;
    const int hd = blockIdx.x & 3, it64 = blockIdx.x >> 2;
    const int q = lane >> 4, r = lane & 15;
    const int i0 = it64 * 64 + ih * 32, ia = i0 + r;
    const float cia = ipk[hd * NN + ia];
    const float cib = ipk[hd * NN + ia + 16];
    const int qs = q * 8;

    __shared__ unsigned lut[16];
    __shared__ float sacc[2][4][10][64][4];   // 81920 B (3-sync tree combine)
    if (threadIdx.x < 16) {
        unsigned m01 = (threadIdx.x * 0x204081u) & 0x01010101u;
        lut[threadIdx.x] = m01 * 0xFFu;    // byte e = 0xFF iff bit e of idx
    }
    __syncthreads();

    f32x4 acc[10] = {};
    const long ones = 0x3838383838383838L;      // fp8 e4m3 1.0 bytes

    const int it0 = js * 16;
    const float* jp = jpkf + (size_t)hd * NN * 2 + 2 * ((it0 << 5) + qs);
    const long*  vp = (const long*)(VtF8 + (size_t)(it0 * 16 + hd * 4) * 512) + lane;
    const uint4* prow = pT4 + (size_t)(js * 4) * NN + ia;

    auto iset = [&](unsigned w, float ci, f32x4* ac,
                    float4 ja, float4 jb, float4 jc, float4 jd,
                    long v0, long v1, long v2, long v3) {
        float p0 = fmaxf(ja.x, ci * ja.y);
        float p1 = fmaxf(ja.z, ci * ja.w);
        float p2 = fmaxf(jb.x, ci * jb.y);
        float p3 = fmaxf(jb.z, ci * jb.w);
        float p4 = fmaxf(jc.x, ci * jc.y);
        float p5 = fmaxf(jc.z, ci * jc.w);
        float p6 = fmaxf(jd.x, ci * jd.y);
        float p7 = fmaxf(jd.z, ci * jd.w);
        I64 af;
        af.i[0] = pkfp8x4(p0, p1, p2, p3) & (int)lut[w & 15u];
        af.i[1] = pkfp8x4(p4, p5, p6, p7) & (int)lut[(w >> 4) & 15u];
        ac[0] = __builtin_amdgcn_mfma_f32_16x16x32_fp8_fp8(af.v, v0, ac[0], 0, 0, 0);
        ac[1] = __builtin_amdgcn_mfma_f32_16x16x32_fp8_fp8(af.v, v1, ac[1], 0, 0, 0);
        ac[2] = __builtin_amdgcn_mfma_f32_16x16x32_fp8_fp8(af.v, v2, ac[2], 0, 0, 0);
        ac[3] = __builtin_amdgcn_mfma_f32_16x16x32_fp8_fp8(af.v, v3, ac[3], 0, 0, 0);
        ac[4] = __builtin_amdgcn_mfma_f32_16x16x32_fp8_fp8(af.v, ones, ac[4], 0, 0, 0);
    };

    #pragma unroll 1
    for (int g = 0; g < 4; g++) {
        uint4 wga = prow[(size_t)g * NN];
        uint4 wgb = prow[(size_t)g * NN + 16];
        #pragma unroll
        for (int u = 0; u < 4; u++) {
            unsigned wa = (u == 0 ? wga.x : u == 1 ? wga.y : u == 2 ? wga.z : wga.w) >> qs;
            unsigned wb = (u == 0 ? wgb.x : u == 1 ? wgb.y : u == 2 ? wgb.z : wgb.w) >> qs;
            const float4* jpv = (const float4*)jp;
            float4 ja = jpv[0], jb = jpv[1], jc = jpv[2], jd = jpv[3];
            long v0 = vp[0], v1 = vp[64], v2 = vp[128], v3 = vp[192];
            iset(wa, cia, acc,     ja, jb, jc, jd, v0, v1, v2, v3);
            iset(wb, cib, acc + 5, ja, jb, jc, jd, v0, v1, v2, v3);
            jp += 64; vp += 1024;
        }
    }

    // 3-sync tree combine within each i-half: 8 waves -> 1.
    if (js >= 4) {
        #pragma unroll
        for (int t = 0; t < 10; t++)
            *(f32x4*)&sacc[ih][js - 4][t][lane][0] = acc[t];
    }
    __syncthreads();
    if (js < 4) {
        #pragma unroll
        for (int t = 0; t < 10; t++) {
            f32x4 o = *(const f32x4*)&sacc[ih][js][t][lane][0];
            acc[t][0] += o[0]; acc[t][1] += o[1];
            acc[t][2] += o[2]; acc[t][3] += o[3];
        }
    }
    __syncthreads();
    if (js >= 1 && js < 4) {
        #pragma unroll
        for (int t = 0; t < 10; t++)
            *(f32x4*)&sacc[ih][js - 1][t][lane][0] = acc[t];
    }
    __syncthreads();
    if (js == 0) {
        #pragma unroll 1
        for (int gg = 0; gg < 3; gg++)
            #pragma unroll
            for (int t = 0; t < 10; t++) {
                f32x4 o = *(const f32x4*)&sacc[ih][gg][t][lane][0];
                acc[t][0] += o[0]; acc[t][1] += o[1];
                acc[t][2] += o[2]; acc[t][3] += o[3];
            }
        #pragma unroll
        for (int reg = 0; reg < 4; reg++) {
            float inva = 1.f / acc[4][reg];
            float invb = 1.f / acc[9][reg];
            int rowa = i0 + q * 4 + reg;
            #pragma unroll
            for (int t = 0; t < 4; t++) {
                out[(size_t)rowa * NF + hd * 64 + t * 16 + r] = acc[t][reg] * inva;
                out[(size_t)(rowa + 16) * NF + hd * 64 + t * 16 + r] = acc[t + 5][reg] * invb;
            }
        }
    }
}

extern "C" void kernel_launch(void* const* d_in, const int* in_sizes, int n_in,
                              void* d_out, int out_size, void* d_ws, size_t ws_size,
                              hipStream_t stream) {
    const float* x   = (const float*)d_in[0];
    const int*   adj = (const int*)d_in[1];
    const float* W   = (const float*)d_in[2];
    const float* a   = (const float*)d_in[3];
    float* out = (float*)d_out;

    char* ws = (char*)d_ws;
    unsigned char* VtF8 = (unsigned char*)ws;              // 1 MiB
    unsigned*      pT   = (unsigned*)(ws + 1048576);       // 2 MiB
    float*         ipk  = (float*)(ws + 3145728);          // 64 KiB
    float2*        jpk  = (float2*)(ws + 3211264);         // 128 KiB

    stage2  <<<16640, 256, 0, stream>>>(x, W, a, adj, VtF8, ipk, jpk, pT);
    gat_attn<<<256, 1024, 0, stream>>>((const uint4*)pT, ipk, (const float*)jpk, VtF8, out);
}